// Round 13
// baseline (298.408 us; speedup 1.0000x reference)
//
#include <hip/hip_runtime.h>
#include <hip/hip_bf16.h>
#include <math.h>

// Problem constants
#define BB 4
#define SS 2048
#define DD 256
#define HH 8
#define HSZ 32

typedef __attribute__((ext_vector_type(8))) short short8;   // 8 bf16 (4 VGPRs)
typedef __attribute__((ext_vector_type(4))) float f32x4;    // MFMA C/D frag

__device__ __forceinline__ float gelu_f(float x) {
    float x3 = x * x * x;
    float z = 0.7978845608028654f * fmaf(0.044715f, x3, x);
    float e = __expf(2.0f * z);
    float t = 1.0f - 2.0f / (e + 1.0f);
    return 0.5f * x * (1.0f + t);
}

__device__ __forceinline__ unsigned short f2bf(float f) {
    unsigned int u = __float_as_uint(f);
    u = (u + 0x7fffu + ((u >> 16) & 1u)) >> 16;
    return (unsigned short)u;
}

// pack two fp32 -> two bf16 (truncation; bias cancels in softmax p/sum(p))
__device__ __forceinline__ unsigned int pack_bf16_tr(float a, float b) {
    return (__float_as_uint(a) >> 16) | (__float_as_uint(b) & 0xffff0000u);
}

// ---------------- Wave-per-token LayerNorm body (no barriers) ----------------
template<bool HASRES>
__device__ __forceinline__ void ln_wave_body(
    int t, int lane,
    const float* __restrict__ x, const float* __restrict__ addin,
    const float* __restrict__ g, const float* __restrict__ bvec,
    float* __restrict__ resid_out, unsigned short* __restrict__ oln_bf)
{
    const int base = t * DD + lane * 4;
    float4 v4 = *(const float4*)&x[base];
    if (HASRES) {
        float4 a4 = *(const float4*)&addin[base];
        v4.x += a4.x; v4.y += a4.y; v4.z += a4.z; v4.w += a4.w;
        *(float4*)&resid_out[base] = v4;
    }
    float s = (v4.x + v4.y) + (v4.z + v4.w);
    #pragma unroll
    for (int o = 1; o < 64; o <<= 1) s += __shfl_xor(s, o);
    float mean = s * (1.0f / 256.0f);
    float dx = v4.x - mean, dy = v4.y - mean, dz = v4.z - mean, dw = v4.w - mean;
    float q = (dx * dx + dy * dy) + (dz * dz + dw * dw);
    #pragma unroll
    for (int o = 1; o < 64; o <<= 1) q += __shfl_xor(q, o);
    float r = rsqrtf(q * (1.0f / 256.0f) + 1e-6f);
    const float4 g4 = *(const float4*)&g[lane * 4];
    const float4 b4 = *(const float4*)&bvec[lane * 4];
    ushort4 o4;
    o4.x = f2bf(dx * r * g4.x + b4.x);
    o4.y = f2bf(dy * r * g4.y + b4.y);
    o4.z = f2bf(dz * r * g4.z + b4.z);
    o4.w = f2bf(dw * r * g4.w + b4.w);
    *(ushort4*)&oln_bf[base] = o4;
}

// ---------------- Fused prep: weight transposes (0..1279) + LN1 (1280..3327) + maskf (3328..3335) ----------------
__global__ __launch_bounds__(256) void prep_kernel(
    const float* __restrict__ Wq, const float* __restrict__ Wk,
    const float* __restrict__ Wv, const float* __restrict__ Wo1,
    const float* __restrict__ Wo2, unsigned short* __restrict__ wt,
    const float* __restrict__ x, const float* __restrict__ ln1g,
    const float* __restrict__ ln1b, unsigned short* __restrict__ h_bf,
    const int* __restrict__ mask, float* __restrict__ maskf)
{
    if (blockIdx.x < 1280) {
        const int WCp = 3 * DD * DD;
        const int WMp = DD * DD;
        const float* src; unsigned short* dst; int R, rel;
        int i = blockIdx.x;
        if (i < 1152) {
            int seg = i / 192; rel = i % 192; R = 768;
            src = seg == 0 ? Wq : seg == 1 ? Wq + WCp : seg == 2 ? Wk :
                  seg == 3 ? Wk + WCp : seg == 4 ? Wv : Wv + WCp;
            dst = wt + (size_t)seg * WCp;
        } else {
            int j = i - 1152; int seg = j / 64; rel = j % 64; R = 256;
            src = seg == 0 ? Wo1 : Wo2;
            dst = wt + (size_t)6 * WCp + (size_t)seg * WMp;
        }
        __shared__ unsigned short t[32][33];
        const int tx = threadIdx.x & 31, ty = threadIdx.x >> 5;
        const int r0 = (rel / 8) * 32, c0 = (rel % 8) * 32;
        #pragma unroll
        for (int j = 0; j < 32; j += 8)
            t[ty + j][tx] = f2bf(src[(r0 + ty + j) * 256 + c0 + tx]);
        __syncthreads();
        #pragma unroll
        for (int j = 0; j < 32; j += 8)
            dst[(size_t)(c0 + ty + j) * R + r0 + tx] = t[tx][ty + j];
    } else if (blockIdx.x < 3328) {
        const int wv = threadIdx.x >> 6, lane = threadIdx.x & 63;
        ln_wave_body<false>((blockIdx.x - 1280) * 4 + wv, lane,
                            x, nullptr, ln1g, ln1b, nullptr, h_bf);
    } else {
        const float M_ON  = -8.0f * 1.4426950408889634f;
        const float M_OFF = -1.442695e30f;
        int i = (blockIdx.x - 3328) * 1024 + threadIdx.x * 4;
        int4 m4 = *(const int4*)&mask[i];
        float4 f4;
        f4.x = m4.x ? M_ON : M_OFF;
        f4.y = m4.y ? M_ON : M_OFF;
        f4.z = m4.z ? M_ON : M_OFF;
        f4.w = m4.w ? M_ON : M_OFF;
        *(float4*)&maskf[i] = f4;
    }
}

// ---------------- Fused dual-layer conv3, 16-token tiles, frag-layout outputs ----------------
// Outputs are written in MFMA-fragment order so attn can dwordx4 them directly:
//   Q/K: [bh][c][half*512 + lane*8 + j]  (lane=(d>>3)*16+(key&15), j=d&7)
//   V:   [bh][c][(d>>4)*512 + half*256 + ((key&15)>>3)*128 + (d&15)*8 + (key&7)]
__global__ __launch_bounds__(256) void convdual_kernel(
    const unsigned short* __restrict__ in,
    const unsigned short* __restrict__ W0a, const unsigned short* __restrict__ W0b,
    const unsigned short* __restrict__ W0c,
    const unsigned short* __restrict__ W1a, const unsigned short* __restrict__ W1b,
    const unsigned short* __restrict__ W1c,
    const float* __restrict__ ba, const float* __restrict__ bb,
    const float* __restrict__ bc,
    unsigned short* __restrict__ oQ, unsigned short* __restrict__ oK,
    unsigned short* __restrict__ oV, int S)
{
    constexpr int LDW = 264;
    __shared__ __align__(16) unsigned short stage[20 * LDW];  // 10.6 KB; reused as frag buffer (8 KB)
    __shared__ __align__(16) unsigned short inter[18 * LDW];  // 9.5 KB

    const int set = blockIdx.x % 3;
    const int tile = blockIdx.x / 3;
    const unsigned short* W0 = set == 0 ? W0a : (set == 1 ? W0b : W0c);
    const unsigned short* W1 = set == 0 ? W1a : (set == 1 ? W1b : W1c);
    const float* bias         = set == 0 ? ba  : (set == 1 ? bb  : bc);
    unsigned short* outp      = set == 0 ? oQ  : (set == 1 ? oK  : oV);

    const int tid = threadIdx.x;
    const int lane = tid & 63, wv = tid >> 6;
    const int lm = lane & 15, lq = lane >> 4;
    const int tpb = S / 16;
    const int b = tile / tpb;
    const int s0 = (tile % tpb) * 16;
    const int NC = S / 32;

    // stage tokens s0-2 .. s0+17 (rows 0..19)
    for (int i = tid; i < 20 * 32; i += 256) {
        int r = i >> 5, c8 = (i & 31) << 3;
        int s = s0 + r - 2;
        int4 val = make_int4(0, 0, 0, 0);
        if (s >= 0 && s < S)
            val = *(const int4*)&in[(size_t)(b * S + s) * 256 + c8];
        *(int4*)&stage[r * LDW + c8] = val;
    }

    const int n0 = wv * 64;

    // ---- layer 1: rows j=0..17 (token s0-1+j), 2 M-tiles, clamped halo reads ----
    {
        f32x4 acc[2][4];
        #pragma unroll
        for (int mt = 0; mt < 2; ++mt)
            #pragma unroll
            for (int nt = 0; nt < 4; ++nt) acc[mt][nt] = (f32x4){0.f, 0.f, 0.f, 0.f};

        const unsigned short* wp = W0 + (size_t)(n0 + lm) * 768 + lq * 8;
        short8 bf[4][4];
        #pragma unroll
        for (int p = 0; p < 3; ++p)
            #pragma unroll
            for (int nt = 0; nt < 4; ++nt)
                bf[p][nt] = *(const short8*)(wp + p * 32 + (size_t)nt * 16 * 768);

        __syncthreads();
        #pragma unroll
        for (int it = 0; it < 24; ++it) {
            if (it + 3 < 24) {
                #pragma unroll
                for (int nt = 0; nt < 4; ++nt)
                    bf[(it + 3) & 3][nt] =
                        *(const short8*)(wp + (it + 3) * 32 + (size_t)nt * 16 * 768);
            }
            const int kk = it >> 3;
            const int icc = (it & 7) * 32 + lq * 8;
            int r1 = kk + 16 + lm; r1 = r1 > 19 ? 19 : r1;  // clamped rows feed only discarded outputs
            short8 a0 = *(const short8*)&stage[(kk + lm) * LDW + icc];
            short8 a1 = *(const short8*)&stage[r1 * LDW + icc];
            #pragma unroll
            for (int nt = 0; nt < 4; ++nt) {
                acc[0][nt] = __builtin_amdgcn_mfma_f32_16x16x32_bf16(a0, bf[it & 3][nt], acc[0][nt], 0, 0, 0);
                acc[1][nt] = __builtin_amdgcn_mfma_f32_16x16x32_bf16(a1, bf[it & 3][nt], acc[1][nt], 0, 0, 0);
            }
        }

        #pragma unroll
        for (int mt = 0; mt < 2; ++mt)
            #pragma unroll
            for (int nt = 0; nt < 4; ++nt) {
                int ch = n0 + nt * 16 + lm;
                float bv = bias[ch];
                #pragma unroll
                for (int r = 0; r < 4; ++r) {
                    int j = mt * 16 + lq * 4 + r;
                    if (j < 18) {
                        int token = s0 - 1 + j;
                        // reference zero-pads LAYER-1 OUTPUT at sequence edges
                        unsigned short v = (token >= 0 && token < S)
                            ? f2bf(gelu_f(acc[mt][nt][r] + bv)) : (unsigned short)0;
                        inter[j * LDW + ch] = v;
                    }
                }
            }
    }
    __syncthreads();

    // ---- layer 2: out rows m=0..15 (token s0+m), 1 M-tile ----
    f32x4 acc2[4];
    #pragma unroll
    for (int nt = 0; nt < 4; ++nt) acc2[nt] = (f32x4){0.f, 0.f, 0.f, 0.f};
    {
        const unsigned short* wp = W1 + (size_t)(n0 + lm) * 768 + lq * 8;
        short8 bf[4][4];
        #pragma unroll
        for (int p = 0; p < 3; ++p)
            #pragma unroll
            for (int nt = 0; nt < 4; ++nt)
                bf[p][nt] = *(const short8*)(wp + p * 32 + (size_t)nt * 16 * 768);

        #pragma unroll
        for (int it = 0; it < 24; ++it) {
            if (it + 3 < 24) {
                #pragma unroll
                for (int nt = 0; nt < 4; ++nt)
                    bf[(it + 3) & 3][nt] =
                        *(const short8*)(wp + (it + 3) * 32 + (size_t)nt * 16 * 768);
            }
            const int kk = it >> 3;
            const int icc = (it & 7) * 32 + lq * 8;
            short8 a0 = *(const short8*)&inter[(kk + lm) * LDW + icc];
            #pragma unroll
            for (int nt = 0; nt < 4; ++nt)
                acc2[nt] = __builtin_amdgcn_mfma_f32_16x16x32_bf16(a0, bf[it & 3][nt], acc2[nt], 0, 0, 0);
        }
    }

    // ---- epilogue: pack into frag order via stage, then coalesced writeout ----
    __syncthreads();  // stage free (layer-1 reads done)
    const int c = s0 >> 5, half = (s0 >> 4) & 1;
    if (set < 2) {
        // Q/K frag: f = (h*64 + (d>>3)*16 + t)*8 + (d&7)
        #pragma unroll
        for (int nt = 0; nt < 4; ++nt) {
            int o = n0 + nt * 16 + lm;
            int d = o & 31, h = o >> 5;
            float bv = bias[256 + o];
            #pragma unroll
            for (int r = 0; r < 4; ++r) {
                int t = lq * 4 + r;
                stage[(h * 64 + (d >> 3) * 16 + t) * 8 + (d & 7)] =
                    f2bf(acc2[nt][r] + bv);
            }
        }
        __syncthreads();
        int h = tid >> 5;
        size_t dst = ((size_t)(b * 8 + h) * NC + c) * 1024 + half * 512 + (tid & 31) * 16;
        int4 v0 = *(const int4*)&stage[tid * 16];
        int4 v1 = *(const int4*)&stage[tid * 16 + 8];
        *(int4*)&outp[dst] = v0;
        *(int4*)&outp[dst + 8] = v1;
    } else {
        // V frag: f = ((h*2 + (d>>4))*32 + (t>>3)*16 + (d&15))*8 + (t&7)
        #pragma unroll
        for (int nt = 0; nt < 4; ++nt) {
            int o = n0 + nt * 16 + lm;
            int d = o & 31, h = o >> 5;
            float bv = bias[256 + o];
            #pragma unroll
            for (int r = 0; r < 4; ++r) {
                int t = lq * 4 + r;
                stage[((h * 2 + (d >> 4)) * 32 + (t >> 3) * 16 + (d & 15)) * 8 + (t & 7)] =
                    f2bf(acc2[nt][r] + bv);
            }
        }
        __syncthreads();
        int h = tid >> 5, dh = (tid >> 4) & 1;
        size_t dst = ((size_t)(b * 8 + h) * NC + c) * 1024 + dh * 512 + half * 256 + (tid & 15) * 16;
        int4 v0 = *(const int4*)&stage[tid * 16];
        int4 v1 = *(const int4*)&stage[tid * 16 + 8];
        *(int4*)&outp[dst] = v0;
        *(int4*)&outp[dst + 8] = v1;
    }
}

// ---------------- Fused tail: LN2 + MLP1(gelu) + MLP2 + residual ----------------
__global__ __launch_bounds__(256) void tail_kernel(
    const float* __restrict__ x, const float* __restrict__ attn,
    const float* __restrict__ g2, const float* __restrict__ b2,
    const unsigned short* __restrict__ W1, const float* __restrict__ bo1,
    const unsigned short* __restrict__ W2, const float* __restrict__ bo2,
    float* __restrict__ out, int S)
{
    constexpr int LDW = 264;
    __shared__ __align__(16) unsigned short h_lds[16 * LDW];
    __shared__ __align__(16) unsigned short h2_lds[16 * LDW];
    __shared__ __align__(16) float resid_lds[16][DD];

    const int tid = threadIdx.x;
    const int lane = tid & 63, wv = tid >> 6;
    const int lm = lane & 15, lq = lane >> 4;
    const int t0 = blockIdx.x * 16;

    #pragma unroll
    for (int j = 0; j < 4; ++j) {
        int t = wv * 4 + j;
        int base = (t0 + t) * DD + lane * 4;
        float4 v4 = *(const float4*)&x[base];
        float4 a4 = *(const float4*)&attn[base];
        v4.x += a4.x; v4.y += a4.y; v4.z += a4.z; v4.w += a4.w;
        *(float4*)&resid_lds[t][lane * 4] = v4;
        float s = (v4.x + v4.y) + (v4.z + v4.w);
        #pragma unroll
        for (int o = 1; o < 64; o <<= 1) s += __shfl_xor(s, o);
        float mean = s * (1.0f / 256.0f);
        float dx = v4.x - mean, dy = v4.y - mean, dz = v4.z - mean, dw = v4.w - mean;
        float q = (dx * dx + dy * dy) + (dz * dz + dw * dw);
        #pragma unroll
        for (int o = 1; o < 64; o <<= 1) q += __shfl_xor(q, o);
        float r = rsqrtf(q * (1.0f / 256.0f) + 1e-6f);
        const float4 g4 = *(const float4*)&g2[lane * 4];
        const float4 b4 = *(const float4*)&b2[lane * 4];
        ushort4 o4;
        o4.x = f2bf(dx * r * g4.x + b4.x);
        o4.y = f2bf(dy * r * g4.y + b4.y);
        o4.z = f2bf(dz * r * g4.z + b4.z);
        o4.w = f2bf(dw * r * g4.w + b4.w);
        *(ushort4*)&h_lds[t * LDW + lane * 4] = o4;
    }
    __syncthreads();

    const int n0 = wv * 64;

    {
        f32x4 acc[4];
        #pragma unroll
        for (int nt = 0; nt < 4; ++nt) acc[nt] = (f32x4){0.f, 0.f, 0.f, 0.f};
        const unsigned short* wp = W1 + (size_t)(n0 + lm) * 256 + lq * 8;
        short8 bf[4][4];
        #pragma unroll
        for (int p = 0; p < 3; ++p)
            #pragma unroll
            for (int nt = 0; nt < 4; ++nt)
                bf[p][nt] = *(const short8*)(wp + p * 32 + (size_t)nt * 16 * 256);
        #pragma unroll
        for (int it = 0; it < 8; ++it) {
            if (it + 3 < 8) {
                #pragma unroll
                for (int nt = 0; nt < 4; ++nt)
                    bf[(it + 3) & 3][nt] =
                        *(const short8*)(wp + (it + 3) * 32 + (size_t)nt * 16 * 256);
            }
            short8 a0 = *(const short8*)&h_lds[lm * LDW + it * 32 + lq * 8];
            #pragma unroll
            for (int nt = 0; nt < 4; ++nt)
                acc[nt] = __builtin_amdgcn_mfma_f32_16x16x32_bf16(a0, bf[it & 3][nt], acc[nt], 0, 0, 0);
        }
        #pragma unroll
        for (int nt = 0; nt < 4; ++nt) {
            int ch = n0 + nt * 16 + lm;
            float bv = bo1[ch];
            #pragma unroll
            for (int r = 0; r < 4; ++r) {
                int tok = lq * 4 + r;
                h2_lds[tok * LDW + ch] = f2bf(gelu_f(acc[nt][r] + bv));
            }
        }
    }
    __syncthreads();

    {
        f32x4 acc[4];
        #pragma unroll
        for (int nt = 0; nt < 4; ++nt) acc[nt] = (f32x4){0.f, 0.f, 0.f, 0.f};
        const unsigned short* wp = W2 + (size_t)(n0 + lm) * 256 + lq * 8;
        short8 bf[4][4];
        #pragma unroll
        for (int p = 0; p < 3; ++p)
            #pragma unroll
            for (int nt = 0; nt < 4; ++nt)
                bf[p][nt] = *(const short8*)(wp + p * 32 + (size_t)nt * 16 * 256);
        #pragma unroll
        for (int it = 0; it < 8; ++it) {
            if (it + 3 < 8) {
                #pragma unroll
                for (int nt = 0; nt < 4; ++nt)
                    bf[(it + 3) & 3][nt] =
                        *(const short8*)(wp + (it + 3) * 32 + (size_t)nt * 16 * 256);
            }
            short8 a0 = *(const short8*)&h2_lds[lm * LDW + it * 32 + lq * 8];
            #pragma unroll
            for (int nt = 0; nt < 4; ++nt)
                acc[nt] = __builtin_amdgcn_mfma_f32_16x16x32_bf16(a0, bf[it & 3][nt], acc[nt], 0, 0, 0);
        }
        #pragma unroll
        for (int nt = 0; nt < 4; ++nt) {
            int ch = n0 + nt * 16 + lm;
            float bv = bo2[ch];
            #pragma unroll
            for (int r = 0; r < 4; ++r) {
                int tok = lq * 4 + r;
                out[(size_t)(t0 + tok) * DD + ch] = acc[nt][r] + bv + resid_lds[tok][ch];
            }
        }
    }
}

// ---------------- MFMA flash attention v6: frag-ready global K/V, NO barriers ----------------
__global__ __launch_bounds__(256) void attn_mfma_kernel(
    const unsigned short* __restrict__ Qf, const unsigned short* __restrict__ Kf,
    const unsigned short* __restrict__ Vf, const float* __restrict__ maskf,
    float* __restrict__ Out, int S, int H)
{
    constexpr int LDP = 40;
    __shared__ __align__(16) unsigned short p_lds[4][16 * LDP];

    const int bh = ((blockIdx.x & 7) << 2) | ((blockIdx.x >> 3) & 3);  // XCD locality
    const int qt = (blockIdx.x >> 5) * 64;
    const int b = bh / H;
    const int tid = threadIdx.x;
    const int lane = tid & 63, wv = tid >> 6;
    const int lm = lane & 15, lq = lane >> 4;
    const int q0 = qt + wv * 16;
    const int NC = S / 32;

    const size_t base = (size_t)bh * NC * 1024;
    short8 qfrag = *(const short8*)&Qf[base + (size_t)(q0 >> 5) * 1024
                                      + ((q0 >> 4) & 1) * 512 + lane * 8];
    const unsigned short* kp = Kf + base + lane * 8;
    const unsigned short* vp = Vf + base + lane * 8;

    short8 ones;
    #pragma unroll
    for (int j = 0; j < 8; ++j) ones[j] = (short)0x3F80;  // bf16 1.0

    f32x4 o0 = {0.f, 0.f, 0.f, 0.f}, o1 = {0.f, 0.f, 0.f, 0.f};
    const f32x4 zf = {0.f, 0.f, 0.f, 0.f};
    float l[4] = {0.f, 0.f, 0.f, 0.f};

    const float scale2 = 0.17677669529663687f * 1.4426950408889634f;
    const float* mp0 = maskf + b * S + lq * 4;
    const float* mp1 = mp0 + 16;

    unsigned short* pw = p_lds[wv];
    const int pst = lm * LDP + lq * 4;
    const int prd = lm * LDP + lq * 8;

    // register double-buffer prefetch of K/V frags (L2-resident after XCD swizzle)
    short8 k0c = *(const short8*)(kp);
    short8 k1c = *(const short8*)(kp + 512);
    short8 v0c = *(const short8*)(vp);
    short8 v1c = *(const short8*)(vp + 512);

    for (int c = 0; c < NC; ++c) {
        int cn = c + 1 < NC ? c + 1 : c;   // branchless prefetch index
        short8 k0n = *(const short8*)(kp + (size_t)cn * 1024);
        short8 k1n = *(const short8*)(kp + (size_t)cn * 1024 + 512);
        short8 v0n = *(const short8*)(vp + (size_t)cn * 1024);
        short8 v1n = *(const short8*)(vp + (size_t)cn * 1024 + 512);

        // transposed scores: D[m=key][n=query]
        f32x4 s0 = __builtin_amdgcn_mfma_f32_16x16x32_bf16(k0c, qfrag, zf, 0, 0, 0);
        f32x4 s1 = __builtin_amdgcn_mfma_f32_16x16x32_bf16(k1c, qfrag, zf, 0, 0, 0);

        float4 mf0 = *(const float4*)(mp0 + c * 32);
        float4 mf1 = *(const float4*)(mp1 + c * 32);

        float p[8];
        p[0] = exp2f(fmaf(s0[0], scale2, mf0.x));
        p[1] = exp2f(fmaf(s0[1], scale2, mf0.y));
        p[2] = exp2f(fmaf(s0[2], scale2, mf0.z));
        p[3] = exp2f(fmaf(s0[3], scale2, mf0.w));
        p[4] = exp2f(fmaf(s1[0], scale2, mf1.x));
        p[5] = exp2f(fmaf(s1[1], scale2, mf1.y));
        p[6] = exp2f(fmaf(s1[2], scale2, mf1.z));
        p[7] = exp2f(fmaf(s1[3], scale2, mf1.w));

        uint2 w0, w1;
        w0.x = pack_bf16_tr(p[0], p[1]); w0.y = pack_bf16_tr(p[2], p[3]);
        w1.x = pack_bf16_tr(p[4], p[5]); w1.y = pack_bf16_tr(p[6], p[7]);
        *(uint2*)&pw[pst] = w0;
        *(uint2*)&pw[pst + 16] = w1;

        short8 pA = *(const short8*)&pw[prd];   // wave-private, no barrier

        f32x4 lf = __builtin_amdgcn_mfma_f32_16x16x32_bf16(pA, ones, zf, 0, 0, 0);
        o0 = __builtin_amdgcn_mfma_f32_16x16x32_bf16(pA, v0c, o0, 0, 0, 0);
        o1 = __builtin_amdgcn_mfma_f32_16x16x32_bf16(pA, v1c, o1, 0, 0, 0);
        #pragma unroll
        for (int r = 0; r < 4; ++r) l[r] += lf[r];

        k0c = k0n; k1c = k1n; v0c = v0n; v1c = v1n;
    }

    #pragma unroll
    for (int r = 0; r < 4; ++r) {
        float inv = 1.0f / l[r];
        size_t ob = (size_t)(b * S + q0 + lq * 4 + r) * 256 + (bh % H) * 32;
        Out[ob + lm] = o0[r] * inv;
        Out[ob + 16 + lm] = o1[r] * inv;
    }
}

extern "C" void kernel_launch(void* const* d_in, const int* in_sizes, int n_in,
                              void* d_out, int out_size, void* d_ws, size_t ws_size,
                              hipStream_t stream) {
    (void)in_sizes; (void)n_in; (void)out_size; (void)ws_size;
    const float* x    = (const float*)d_in[0];
    const float* ln1g = (const float*)d_in[1];
    const float* ln1b = (const float*)d_in[2];
    const float* Wq   = (const float*)d_in[3];
    const float* bq   = (const float*)d_in[4];
    const float* Wk   = (const float*)d_in[5];
    const float* bk   = (const float*)d_in[6];
    const float* Wv   = (const float*)d_in[7];
    const float* bv   = (const float*)d_in[8];
    const float* ln2g = (const float*)d_in[9];
    const float* ln2b = (const float*)d_in[10];
    const float* Wo1  = (const float*)d_in[11];
    const float* bo1  = (const float*)d_in[12];
    const float* Wo2  = (const float*)d_in[13];
    const float* bo2  = (const float*)d_in[14];
    const int*   mask = (const int*)d_in[15];
    float* out = (float*)d_out;

    const int S = SS, H = HH;
    const int T = BB * SS;                 // 8192 tokens
    const size_t NE = (size_t)T * DD;      // 2M elements
    float* ws    = (float*)d_ws;
    float* attn  = ws + 0 * NE;
    float* maskf = ws + 1 * NE;
    unsigned short* qf_g  = (unsigned short*)(ws + 2 * NE);   // frag-packed Q
    unsigned short* kf_g  = qf_g + NE;                        // frag-packed K
    unsigned short* h_bf  = kf_g + NE;
    unsigned short* wt    = h_bf + NE;
    const int WC = 3 * DD * DD;            // 196608
    const int WM = DD * DD;
    unsigned short* wtq0 = wt;
    unsigned short* wtq1 = wt + WC;
    unsigned short* wtk0 = wt + 2 * WC;
    unsigned short* wtk1 = wt + 3 * WC;
    unsigned short* wtv0 = wt + 4 * WC;
    unsigned short* wtv1 = wt + 5 * WC;
    unsigned short* wto1 = wt + 6 * WC;
    unsigned short* wto2 = wt + 6 * WC + WM;
    unsigned short* vf_g = wt + 6 * WC + 2 * WM;   // frag-packed V

    // fused: 8 weight transposes + LN1 + mask->float
    prep_kernel<<<1280 + T / 4 + 8, 256, 0, stream>>>(
        Wq, Wk, Wv, Wo1, Wo2, wt, x, ln1g, ln1b, h_bf, mask, maskf);

    // fused dual-layer temporal encoders; outputs frag-packed Q/K/V
    convdual_kernel<<<(T / 16) * 3, 256, 0, stream>>>(
        h_bf, wtq0, wtk0, wtv0, wtq1, wtk1, wtv1, bq, bk, bv,
        qf_g, kf_g, vf_g, S);

    // barrier-free MFMA attention -> attn (fp32)
    attn_mfma_kernel<<<BB * H * (S / 64), 256, 0, stream>>>(qf_g, kf_g, vf_g, maskf, attn, S, H);

    // fused tail: LN2 + MLP1 + GELU + MLP2 + residual -> out
    tail_kernel<<<T / 16, 256, 0, stream>>>(
        x, attn, ln2g, ln2b, wto1, bo1, wto2, bo2, out, S);
}

// Round 14
// 240.426 us; speedup vs baseline: 1.2412x; 1.2412x over previous
//
#include <hip/hip_runtime.h>
#include <hip/hip_bf16.h>
#include <math.h>

// Problem constants
#define BB 4
#define SS 2048
#define DD 256
#define HH 8
#define HSZ 32

typedef __attribute__((ext_vector_type(8))) short short8;   // 8 bf16 (4 VGPRs)
typedef __attribute__((ext_vector_type(4))) float f32x4;    // MFMA C/D frag

__device__ __forceinline__ float gelu_f(float x) {
    float x3 = x * x * x;
    float z = 0.7978845608028654f * fmaf(0.044715f, x3, x);
    float e = __expf(2.0f * z);
    float t = 1.0f - 2.0f / (e + 1.0f);
    return 0.5f * x * (1.0f + t);
}

__device__ __forceinline__ unsigned short f2bf(float f) {
    unsigned int u = __float_as_uint(f);
    u = (u + 0x7fffu + ((u >> 16) & 1u)) >> 16;
    return (unsigned short)u;
}

// pack two fp32 -> two bf16 (truncation; bias cancels in softmax p/sum(p))
__device__ __forceinline__ unsigned int pack_bf16_tr(float a, float b) {
    return (__float_as_uint(a) >> 16) | (__float_as_uint(b) & 0xffff0000u);
}

// ---------------- Wave-per-token LayerNorm body (no barriers) ----------------
template<bool HASRES>
__device__ __forceinline__ void ln_wave_body(
    int t, int lane,
    const float* __restrict__ x, const float* __restrict__ addin,
    const float* __restrict__ g, const float* __restrict__ bvec,
    float* __restrict__ resid_out, unsigned short* __restrict__ oln_bf)
{
    const int base = t * DD + lane * 4;
    float4 v4 = *(const float4*)&x[base];
    if (HASRES) {
        float4 a4 = *(const float4*)&addin[base];
        v4.x += a4.x; v4.y += a4.y; v4.z += a4.z; v4.w += a4.w;
        *(float4*)&resid_out[base] = v4;
    }
    float s = (v4.x + v4.y) + (v4.z + v4.w);
    #pragma unroll
    for (int o = 1; o < 64; o <<= 1) s += __shfl_xor(s, o);
    float mean = s * (1.0f / 256.0f);
    float dx = v4.x - mean, dy = v4.y - mean, dz = v4.z - mean, dw = v4.w - mean;
    float q = (dx * dx + dy * dy) + (dz * dz + dw * dw);
    #pragma unroll
    for (int o = 1; o < 64; o <<= 1) q += __shfl_xor(q, o);
    float r = rsqrtf(q * (1.0f / 256.0f) + 1e-6f);
    const float4 g4 = *(const float4*)&g[lane * 4];
    const float4 b4 = *(const float4*)&bvec[lane * 4];
    ushort4 o4;
    o4.x = f2bf(dx * r * g4.x + b4.x);
    o4.y = f2bf(dy * r * g4.y + b4.y);
    o4.z = f2bf(dz * r * g4.z + b4.z);
    o4.w = f2bf(dw * r * g4.w + b4.w);
    *(ushort4*)&oln_bf[base] = o4;
}

// ---------------- Fused prep: weight transposes (0..1279) + LN1 (1280..3327) + maskf (3328..3335) ----------------
__global__ __launch_bounds__(256) void prep_kernel(
    const float* __restrict__ Wq, const float* __restrict__ Wk,
    const float* __restrict__ Wv, const float* __restrict__ Wo1,
    const float* __restrict__ Wo2, unsigned short* __restrict__ wt,
    const float* __restrict__ x, const float* __restrict__ ln1g,
    const float* __restrict__ ln1b, unsigned short* __restrict__ h_bf,
    const int* __restrict__ mask, float* __restrict__ maskf)
{
    if (blockIdx.x < 1280) {
        const int WCp = 3 * DD * DD;
        const int WMp = DD * DD;
        const float* src; unsigned short* dst; int R, rel;
        int i = blockIdx.x;
        if (i < 1152) {
            int seg = i / 192; rel = i % 192; R = 768;
            src = seg == 0 ? Wq : seg == 1 ? Wq + WCp : seg == 2 ? Wk :
                  seg == 3 ? Wk + WCp : seg == 4 ? Wv : Wv + WCp;
            dst = wt + (size_t)seg * WCp;
        } else {
            int j = i - 1152; int seg = j / 64; rel = j % 64; R = 256;
            src = seg == 0 ? Wo1 : Wo2;
            dst = wt + (size_t)6 * WCp + (size_t)seg * WMp;
        }
        __shared__ unsigned short t[32][33];
        const int tx = threadIdx.x & 31, ty = threadIdx.x >> 5;
        const int r0 = (rel / 8) * 32, c0 = (rel % 8) * 32;
        #pragma unroll
        for (int j = 0; j < 32; j += 8)
            t[ty + j][tx] = f2bf(src[(r0 + ty + j) * 256 + c0 + tx]);
        __syncthreads();
        #pragma unroll
        for (int j = 0; j < 32; j += 8)
            dst[(size_t)(c0 + ty + j) * R + r0 + tx] = t[tx][ty + j];
    } else if (blockIdx.x < 3328) {
        const int wv = threadIdx.x >> 6, lane = threadIdx.x & 63;
        ln_wave_body<false>((blockIdx.x - 1280) * 4 + wv, lane,
                            x, nullptr, ln1g, ln1b, nullptr, h_bf);
    } else {
        const float M_ON  = -8.0f * 1.4426950408889634f;
        const float M_OFF = -1.442695e30f;
        int i = (blockIdx.x - 3328) * 1024 + threadIdx.x * 4;
        int4 m4 = *(const int4*)&mask[i];
        float4 f4;
        f4.x = m4.x ? M_ON : M_OFF;
        f4.y = m4.y ? M_ON : M_OFF;
        f4.z = m4.z ? M_ON : M_OFF;
        f4.w = m4.w ? M_ON : M_OFF;
        *(float4*)&maskf[i] = f4;
    }
}

// ---------------- Fused dual-layer conv3, 32-token tiles, frag-layout outputs ----------------
// Layer-1: 3 M-tiles (rows j=0..33 kept, tokens s0-1+j; layer-1 output zeroed
// outside [0,S) per the reference's SAME padding). Clamped halo A-reads feed
// only discarded j>=34 outputs. Frag-packed epilogue (both 16-token halves):
//   Q/K: [bh][c][half*512 + ((d>>3)*16+t)*8 + (d&7)]
//   V:   [bh][c][(d>>4)*512 + half*256 + ((t>>3)*16+(d&15))*8 + (t&7)]
__global__ __launch_bounds__(256) void convdual_kernel(
    const unsigned short* __restrict__ in,
    const unsigned short* __restrict__ W0a, const unsigned short* __restrict__ W0b,
    const unsigned short* __restrict__ W0c,
    const unsigned short* __restrict__ W1a, const unsigned short* __restrict__ W1b,
    const unsigned short* __restrict__ W1c,
    const float* __restrict__ ba, const float* __restrict__ bb,
    const float* __restrict__ bc,
    unsigned short* __restrict__ oQ, unsigned short* __restrict__ oK,
    unsigned short* __restrict__ oV, int S)
{
    constexpr int LDW = 264;
    __shared__ __align__(16) unsigned short stage[36 * LDW];  // 19 KB; reused as 16 KB frag buffer
    __shared__ __align__(16) unsigned short inter[34 * LDW];  // 18 KB -> 36.1 KB total, 4 blocks/CU

    const int set = blockIdx.x % 3;
    const int tile = blockIdx.x / 3;
    const unsigned short* W0 = set == 0 ? W0a : (set == 1 ? W0b : W0c);
    const unsigned short* W1 = set == 0 ? W1a : (set == 1 ? W1b : W1c);
    const float* bias         = set == 0 ? ba  : (set == 1 ? bb  : bc);
    unsigned short* outp      = set == 0 ? oQ  : (set == 1 ? oK  : oV);

    const int tid = threadIdx.x;
    const int lane = tid & 63, wv = tid >> 6;
    const int lm = lane & 15, lq = lane >> 4;
    const int tpb = S / 32;
    const int b = tile / tpb;
    const int s0 = (tile % tpb) * 32;
    const int NC = S / 32;
    const int c = s0 >> 5;

    // stage tokens s0-2 .. s0+33 (rows 0..35)
    for (int i = tid; i < 36 * 32; i += 256) {
        int r = i >> 5, c8 = (i & 31) << 3;
        int s = s0 + r - 2;
        int4 val = make_int4(0, 0, 0, 0);
        if (s >= 0 && s < S)
            val = *(const int4*)&in[(size_t)(b * S + s) * 256 + c8];
        *(int4*)&stage[r * LDW + c8] = val;
    }

    const int n0 = wv * 64;

    // ---- layer 1: rows j=0..33, 3 M-tiles, clamped halo on tile 2 ----
    {
        f32x4 acc[3][4];
        #pragma unroll
        for (int mt = 0; mt < 3; ++mt)
            #pragma unroll
            for (int nt = 0; nt < 4; ++nt) acc[mt][nt] = (f32x4){0.f, 0.f, 0.f, 0.f};

        const unsigned short* wp = W0 + (size_t)(n0 + lm) * 768 + lq * 8;
        short8 bf[4][4];
        #pragma unroll
        for (int p = 0; p < 3; ++p)
            #pragma unroll
            for (int nt = 0; nt < 4; ++nt)
                bf[p][nt] = *(const short8*)(wp + p * 32 + (size_t)nt * 16 * 768);

        __syncthreads();
        #pragma unroll
        for (int it = 0; it < 24; ++it) {
            if (it + 3 < 24) {
                #pragma unroll
                for (int nt = 0; nt < 4; ++nt)
                    bf[(it + 3) & 3][nt] =
                        *(const short8*)(wp + (it + 3) * 32 + (size_t)nt * 16 * 768);
            }
            const int kk = it >> 3;
            const int icc = (it & 7) * 32 + lq * 8;
            int r2 = kk + 32 + lm; r2 = r2 > 35 ? 35 : r2;  // clamped rows feed discarded outputs only
            short8 a0 = *(const short8*)&stage[(kk + lm) * LDW + icc];
            short8 a1 = *(const short8*)&stage[(kk + 16 + lm) * LDW + icc];
            short8 a2 = *(const short8*)&stage[r2 * LDW + icc];
            #pragma unroll
            for (int nt = 0; nt < 4; ++nt) {
                acc[0][nt] = __builtin_amdgcn_mfma_f32_16x16x32_bf16(a0, bf[it & 3][nt], acc[0][nt], 0, 0, 0);
                acc[1][nt] = __builtin_amdgcn_mfma_f32_16x16x32_bf16(a1, bf[it & 3][nt], acc[1][nt], 0, 0, 0);
                acc[2][nt] = __builtin_amdgcn_mfma_f32_16x16x32_bf16(a2, bf[it & 3][nt], acc[2][nt], 0, 0, 0);
            }
        }

        #pragma unroll
        for (int mt = 0; mt < 3; ++mt)
            #pragma unroll
            for (int nt = 0; nt < 4; ++nt) {
                int ch = n0 + nt * 16 + lm;
                float bv = bias[ch];
                #pragma unroll
                for (int r = 0; r < 4; ++r) {
                    int j = mt * 16 + lq * 4 + r;
                    if (j < 34) {
                        int token = s0 - 1 + j;
                        unsigned short v = (token >= 0 && token < S)
                            ? f2bf(gelu_f(acc[mt][nt][r] + bv)) : (unsigned short)0;
                        inter[j * LDW + ch] = v;
                    }
                }
            }
    }
    __syncthreads();   // layer-1 stage reads complete; stage free after this

    // ---- layer 2: rows m=0..31, 2 M-tiles ----
    f32x4 acc2[2][4];
    #pragma unroll
    for (int mt = 0; mt < 2; ++mt)
        #pragma unroll
        for (int nt = 0; nt < 4; ++nt) acc2[mt][nt] = (f32x4){0.f, 0.f, 0.f, 0.f};
    {
        const unsigned short* wp = W1 + (size_t)(n0 + lm) * 768 + lq * 8;
        short8 bf[4][4];
        #pragma unroll
        for (int p = 0; p < 3; ++p)
            #pragma unroll
            for (int nt = 0; nt < 4; ++nt)
                bf[p][nt] = *(const short8*)(wp + p * 32 + (size_t)nt * 16 * 768);

        #pragma unroll
        for (int it = 0; it < 24; ++it) {
            if (it + 3 < 24) {
                #pragma unroll
                for (int nt = 0; nt < 4; ++nt)
                    bf[(it + 3) & 3][nt] =
                        *(const short8*)(wp + (it + 3) * 32 + (size_t)nt * 16 * 768);
            }
            const int kk = it >> 3;
            const int icc = (it & 7) * 32 + lq * 8;
            short8 a0 = *(const short8*)&inter[(kk + lm) * LDW + icc];
            short8 a1 = *(const short8*)&inter[(kk + 16 + lm) * LDW + icc];
            #pragma unroll
            for (int nt = 0; nt < 4; ++nt) {
                acc2[0][nt] = __builtin_amdgcn_mfma_f32_16x16x32_bf16(a0, bf[it & 3][nt], acc2[0][nt], 0, 0, 0);
                acc2[1][nt] = __builtin_amdgcn_mfma_f32_16x16x32_bf16(a1, bf[it & 3][nt], acc2[1][nt], 0, 0, 0);
            }
        }
    }

    // ---- epilogue: frag-pack both halves into stage, coalesced writeout ----
    __syncthreads();   // all inter reads done; safe to overwrite stage
    if (set < 2) {
        #pragma unroll
        for (int mt = 0; mt < 2; ++mt)       // mt = half
            #pragma unroll
            for (int nt = 0; nt < 4; ++nt) {
                int o = n0 + nt * 16 + lm;
                int d = o & 31, h = o >> 5;
                float bv = bias[256 + o];
                #pragma unroll
                for (int r = 0; r < 4; ++r) {
                    int t = lq * 4 + r;
                    stage[mt * 4096 + (h * 64 + (d >> 3) * 16 + t) * 8 + (d & 7)] =
                        f2bf(acc2[mt][nt][r] + bv);
                }
            }
        __syncthreads();
        int h = tid >> 5;
        size_t base = ((size_t)(b * 8 + h) * NC + c) * 1024;
        #pragma unroll
        for (int half = 0; half < 2; ++half) {
            int4 v0 = *(const int4*)&stage[half * 4096 + tid * 16];
            int4 v1 = *(const int4*)&stage[half * 4096 + tid * 16 + 8];
            size_t dst = base + half * 512 + (tid & 31) * 16;
            *(int4*)&outp[dst] = v0;
            *(int4*)&outp[dst + 8] = v1;
        }
    } else {
        #pragma unroll
        for (int mt = 0; mt < 2; ++mt)
            #pragma unroll
            for (int nt = 0; nt < 4; ++nt) {
                int o = n0 + nt * 16 + lm;
                int d = o & 31, h = o >> 5;
                float bv = bias[256 + o];
                #pragma unroll
                for (int r = 0; r < 4; ++r) {
                    int t = lq * 4 + r;
                    stage[mt * 4096 +
                          ((h * 2 + (d >> 4)) * 32 + (t >> 3) * 16 + (d & 15)) * 8 + (t & 7)] =
                        f2bf(acc2[mt][nt][r] + bv);
                }
            }
        __syncthreads();
        int h = tid >> 5, dh = (tid >> 4) & 1;
        size_t base = ((size_t)(b * 8 + h) * NC + c) * 1024;
        #pragma unroll
        for (int half = 0; half < 2; ++half) {
            int4 v0 = *(const int4*)&stage[half * 4096 + tid * 16];
            int4 v1 = *(const int4*)&stage[half * 4096 + tid * 16 + 8];
            size_t dst = base + dh * 512 + half * 256 + (tid & 15) * 16;
            *(int4*)&outp[dst] = v0;
            *(int4*)&outp[dst + 8] = v1;
        }
    }
}

// ---------------- Fused tail: LN2 + MLP1(gelu) + MLP2 + residual ----------------
__global__ __launch_bounds__(256) void tail_kernel(
    const float* __restrict__ x, const float* __restrict__ attn,
    const float* __restrict__ g2, const float* __restrict__ b2,
    const unsigned short* __restrict__ W1, const float* __restrict__ bo1,
    const unsigned short* __restrict__ W2, const float* __restrict__ bo2,
    float* __restrict__ out, int S)
{
    constexpr int LDW = 264;
    __shared__ __align__(16) unsigned short h_lds[16 * LDW];
    __shared__ __align__(16) unsigned short h2_lds[16 * LDW];
    __shared__ __align__(16) float resid_lds[16][DD];

    const int tid = threadIdx.x;
    const int lane = tid & 63, wv = tid >> 6;
    const int lm = lane & 15, lq = lane >> 4;
    const int t0 = blockIdx.x * 16;

    #pragma unroll
    for (int j = 0; j < 4; ++j) {
        int t = wv * 4 + j;
        int base = (t0 + t) * DD + lane * 4;
        float4 v4 = *(const float4*)&x[base];
        float4 a4 = *(const float4*)&attn[base];
        v4.x += a4.x; v4.y += a4.y; v4.z += a4.z; v4.w += a4.w;
        *(float4*)&resid_lds[t][lane * 4] = v4;
        float s = (v4.x + v4.y) + (v4.z + v4.w);
        #pragma unroll
        for (int o = 1; o < 64; o <<= 1) s += __shfl_xor(s, o);
        float mean = s * (1.0f / 256.0f);
        float dx = v4.x - mean, dy = v4.y - mean, dz = v4.z - mean, dw = v4.w - mean;
        float q = (dx * dx + dy * dy) + (dz * dz + dw * dw);
        #pragma unroll
        for (int o = 1; o < 64; o <<= 1) q += __shfl_xor(q, o);
        float r = rsqrtf(q * (1.0f / 256.0f) + 1e-6f);
        const float4 g4 = *(const float4*)&g2[lane * 4];
        const float4 b4 = *(const float4*)&b2[lane * 4];
        ushort4 o4;
        o4.x = f2bf(dx * r * g4.x + b4.x);
        o4.y = f2bf(dy * r * g4.y + b4.y);
        o4.z = f2bf(dz * r * g4.z + b4.z);
        o4.w = f2bf(dw * r * g4.w + b4.w);
        *(ushort4*)&h_lds[t * LDW + lane * 4] = o4;
    }
    __syncthreads();

    const int n0 = wv * 64;

    {
        f32x4 acc[4];
        #pragma unroll
        for (int nt = 0; nt < 4; ++nt) acc[nt] = (f32x4){0.f, 0.f, 0.f, 0.f};
        const unsigned short* wp = W1 + (size_t)(n0 + lm) * 256 + lq * 8;
        short8 bf[4][4];
        #pragma unroll
        for (int p = 0; p < 3; ++p)
            #pragma unroll
            for (int nt = 0; nt < 4; ++nt)
                bf[p][nt] = *(const short8*)(wp + p * 32 + (size_t)nt * 16 * 256);
        #pragma unroll
        for (int it = 0; it < 8; ++it) {
            if (it + 3 < 8) {
                #pragma unroll
                for (int nt = 0; nt < 4; ++nt)
                    bf[(it + 3) & 3][nt] =
                        *(const short8*)(wp + (it + 3) * 32 + (size_t)nt * 16 * 256);
            }
            short8 a0 = *(const short8*)&h_lds[lm * LDW + it * 32 + lq * 8];
            #pragma unroll
            for (int nt = 0; nt < 4; ++nt)
                acc[nt] = __builtin_amdgcn_mfma_f32_16x16x32_bf16(a0, bf[it & 3][nt], acc[nt], 0, 0, 0);
        }
        #pragma unroll
        for (int nt = 0; nt < 4; ++nt) {
            int ch = n0 + nt * 16 + lm;
            float bv = bo1[ch];
            #pragma unroll
            for (int r = 0; r < 4; ++r) {
                int tok = lq * 4 + r;
                h2_lds[tok * LDW + ch] = f2bf(gelu_f(acc[nt][r] + bv));
            }
        }
    }
    __syncthreads();

    {
        f32x4 acc[4];
        #pragma unroll
        for (int nt = 0; nt < 4; ++nt) acc[nt] = (f32x4){0.f, 0.f, 0.f, 0.f};
        const unsigned short* wp = W2 + (size_t)(n0 + lm) * 256 + lq * 8;
        short8 bf[4][4];
        #pragma unroll
        for (int p = 0; p < 3; ++p)
            #pragma unroll
            for (int nt = 0; nt < 4; ++nt)
                bf[p][nt] = *(const short8*)(wp + p * 32 + (size_t)nt * 16 * 256);
        #pragma unroll
        for (int it = 0; it < 8; ++it) {
            if (it + 3 < 8) {
                #pragma unroll
                for (int nt = 0; nt < 4; ++nt)
                    bf[(it + 3) & 3][nt] =
                        *(const short8*)(wp + (it + 3) * 32 + (size_t)nt * 16 * 256);
            }
            short8 a0 = *(const short8*)&h2_lds[lm * LDW + it * 32 + lq * 8];
            #pragma unroll
            for (int nt = 0; nt < 4; ++nt)
                acc[nt] = __builtin_amdgcn_mfma_f32_16x16x32_bf16(a0, bf[it & 3][nt], acc[nt], 0, 0, 0);
        }
        #pragma unroll
        for (int nt = 0; nt < 4; ++nt) {
            int ch = n0 + nt * 16 + lm;
            float bv = bo2[ch];
            #pragma unroll
            for (int r = 0; r < 4; ++r) {
                int tok = lq * 4 + r;
                out[(size_t)(t0 + tok) * DD + ch] = acc[nt][r] + bv + resid_lds[tok][ch];
            }
        }
    }
}

// ---------------- MFMA flash attention v6: frag-ready global K/V, NO barriers ----------------
__global__ __launch_bounds__(256) void attn_mfma_kernel(
    const unsigned short* __restrict__ Qf, const unsigned short* __restrict__ Kf,
    const unsigned short* __restrict__ Vf, const float* __restrict__ maskf,
    float* __restrict__ Out, int S, int H)
{
    constexpr int LDP = 40;
    __shared__ __align__(16) unsigned short p_lds[4][16 * LDP];

    const int bh = ((blockIdx.x & 7) << 2) | ((blockIdx.x >> 3) & 3);  // XCD locality
    const int qt = (blockIdx.x >> 5) * 64;
    const int b = bh / H;
    const int tid = threadIdx.x;
    const int lane = tid & 63, wv = tid >> 6;
    const int lm = lane & 15, lq = lane >> 4;
    const int q0 = qt + wv * 16;
    const int NC = S / 32;

    const size_t base = (size_t)bh * NC * 1024;
    short8 qfrag = *(const short8*)&Qf[base + (size_t)(q0 >> 5) * 1024
                                      + ((q0 >> 4) & 1) * 512 + lane * 8];
    const unsigned short* kp = Kf + base + lane * 8;
    const unsigned short* vp = Vf + base + lane * 8;

    short8 ones;
    #pragma unroll
    for (int j = 0; j < 8; ++j) ones[j] = (short)0x3F80;  // bf16 1.0

    f32x4 o0 = {0.f, 0.f, 0.f, 0.f}, o1 = {0.f, 0.f, 0.f, 0.f};
    const f32x4 zf = {0.f, 0.f, 0.f, 0.f};
    float l[4] = {0.f, 0.f, 0.f, 0.f};

    const float scale2 = 0.17677669529663687f * 1.4426950408889634f;
    const float* mp0 = maskf + b * S + lq * 4;
    const float* mp1 = mp0 + 16;

    unsigned short* pw = p_lds[wv];
    const int pst = lm * LDP + lq * 4;
    const int prd = lm * LDP + lq * 8;

    short8 k0c = *(const short8*)(kp);
    short8 k1c = *(const short8*)(kp + 512);
    short8 v0c = *(const short8*)(vp);
    short8 v1c = *(const short8*)(vp + 512);

    for (int c = 0; c < NC; ++c) {
        int cn = c + 1 < NC ? c + 1 : c;
        short8 k0n = *(const short8*)(kp + (size_t)cn * 1024);
        short8 k1n = *(const short8*)(kp + (size_t)cn * 1024 + 512);
        short8 v0n = *(const short8*)(vp + (size_t)cn * 1024);
        short8 v1n = *(const short8*)(vp + (size_t)cn * 1024 + 512);

        f32x4 s0 = __builtin_amdgcn_mfma_f32_16x16x32_bf16(k0c, qfrag, zf, 0, 0, 0);
        f32x4 s1 = __builtin_amdgcn_mfma_f32_16x16x32_bf16(k1c, qfrag, zf, 0, 0, 0);

        float4 mf0 = *(const float4*)(mp0 + c * 32);
        float4 mf1 = *(const float4*)(mp1 + c * 32);

        float p[8];
        p[0] = exp2f(fmaf(s0[0], scale2, mf0.x));
        p[1] = exp2f(fmaf(s0[1], scale2, mf0.y));
        p[2] = exp2f(fmaf(s0[2], scale2, mf0.z));
        p[3] = exp2f(fmaf(s0[3], scale2, mf0.w));
        p[4] = exp2f(fmaf(s1[0], scale2, mf1.x));
        p[5] = exp2f(fmaf(s1[1], scale2, mf1.y));
        p[6] = exp2f(fmaf(s1[2], scale2, mf1.z));
        p[7] = exp2f(fmaf(s1[3], scale2, mf1.w));

        uint2 w0, w1;
        w0.x = pack_bf16_tr(p[0], p[1]); w0.y = pack_bf16_tr(p[2], p[3]);
        w1.x = pack_bf16_tr(p[4], p[5]); w1.y = pack_bf16_tr(p[6], p[7]);
        *(uint2*)&pw[pst] = w0;
        *(uint2*)&pw[pst + 16] = w1;

        short8 pA = *(const short8*)&pw[prd];   // wave-private, no barrier

        f32x4 lf = __builtin_amdgcn_mfma_f32_16x16x32_bf16(pA, ones, zf, 0, 0, 0);
        o0 = __builtin_amdgcn_mfma_f32_16x16x32_bf16(pA, v0c, o0, 0, 0, 0);
        o1 = __builtin_amdgcn_mfma_f32_16x16x32_bf16(pA, v1c, o1, 0, 0, 0);
        #pragma unroll
        for (int r = 0; r < 4; ++r) l[r] += lf[r];

        k0c = k0n; k1c = k1n; v0c = v0n; v1c = v1n;
    }

    #pragma unroll
    for (int r = 0; r < 4; ++r) {
        float inv = 1.0f / l[r];
        size_t ob = (size_t)(b * S + q0 + lq * 4 + r) * 256 + (bh % H) * 32;
        Out[ob + lm] = o0[r] * inv;
        Out[ob + 16 + lm] = o1[r] * inv;
    }
}

extern "C" void kernel_launch(void* const* d_in, const int* in_sizes, int n_in,
                              void* d_out, int out_size, void* d_ws, size_t ws_size,
                              hipStream_t stream) {
    (void)in_sizes; (void)n_in; (void)out_size; (void)ws_size;
    const float* x    = (const float*)d_in[0];
    const float* ln1g = (const float*)d_in[1];
    const float* ln1b = (const float*)d_in[2];
    const float* Wq   = (const float*)d_in[3];
    const float* bq   = (const float*)d_in[4];
    const float* Wk   = (const float*)d_in[5];
    const float* bk   = (const float*)d_in[6];
    const float* Wv   = (const float*)d_in[7];
    const float* bv   = (const float*)d_in[8];
    const float* ln2g = (const float*)d_in[9];
    const float* ln2b = (const float*)d_in[10];
    const float* Wo1  = (const float*)d_in[11];
    const float* bo1  = (const float*)d_in[12];
    const float* Wo2  = (const float*)d_in[13];
    const float* bo2  = (const float*)d_in[14];
    const int*   mask = (const int*)d_in[15];
    float* out = (float*)d_out;

    const int S = SS, H = HH;
    const int T = BB * SS;                 // 8192 tokens
    const size_t NE = (size_t)T * DD;      // 2M elements
    float* ws    = (float*)d_ws;
    float* attn  = ws + 0 * NE;
    float* maskf = ws + 1 * NE;
    unsigned short* qf_g  = (unsigned short*)(ws + 2 * NE);   // frag-packed Q
    unsigned short* kf_g  = qf_g + NE;                        // frag-packed K
    unsigned short* h_bf  = kf_g + NE;
    unsigned short* wt    = h_bf + NE;
    const int WC = 3 * DD * DD;            // 196608
    const int WM = DD * DD;
    unsigned short* wtq0 = wt;
    unsigned short* wtq1 = wt + WC;
    unsigned short* wtk0 = wt + 2 * WC;
    unsigned short* wtk1 = wt + 3 * WC;
    unsigned short* wtv0 = wt + 4 * WC;
    unsigned short* wtv1 = wt + 5 * WC;
    unsigned short* wto1 = wt + 6 * WC;
    unsigned short* wto2 = wt + 6 * WC + WM;
    unsigned short* vf_g = wt + 6 * WC + 2 * WM;   // frag-packed V

    // fused: 8 weight transposes + LN1 + mask->float
    prep_kernel<<<1280 + T / 4 + 8, 256, 0, stream>>>(
        Wq, Wk, Wv, Wo1, Wo2, wt, x, ln1g, ln1b, h_bf, mask, maskf);

    // fused dual-layer temporal encoders (32-token tiles); frag-packed Q/K/V out
    convdual_kernel<<<(T / 32) * 3, 256, 0, stream>>>(
        h_bf, wtq0, wtk0, wtv0, wtq1, wtk1, wtv1, bq, bk, bv,
        qf_g, kf_g, vf_g, S);

    // barrier-free MFMA attention -> attn (fp32)
    attn_mfma_kernel<<<BB * H * (S / 64), 256, 0, stream>>>(qf_g, kf_g, vf_g, maskf, attn, S, H);

    // fused tail: LN2 + MLP1 + GELU + MLP2 + residual -> out
    tail_kernel<<<T / 16, 256, 0, stream>>>(
        x, attn, ln2g, ln2b, wto1, bo1, wto2, bo2, out, S);
}